// Round 1
// baseline (368.949 us; speedup 1.0000x reference)
//
#include <hip/hip_runtime.h>
#include <hip/hip_bf16.h>
#include <math.h>
#include <stdint.h>

typedef __bf16 bf16_t;
typedef __bf16 bf16x8 __attribute__((ext_vector_type(8)));
typedef float  f32x4  __attribute__((ext_vector_type(4)));

#define L_LEN 8192
#define MODES 64
#define NCOMP 128      // 2*MODES (Re | Im)
#define M_ROWS 4096    // B * n_env * ch
#define SPLITS 16      // K-splits in stage1

// ---------------------------------------------------------------------------
// Basis tables. Both transposed layouts are generated with COALESCED 16B
// stores: each thread produces 8 consecutive elements of its destination row.
// B1t[n][l]  n<64: cos(2*pi*n*l/L)   n>=64: -sin(2*pi*(n-64)*l/L)   [128][8192]
// B1 [l][n]  same values transposed                                  [8192][128]
// Exact phase reduction: (k*l) mod 8192 is exact in integers.
// ---------------------------------------------------------------------------
__global__ __launch_bounds__(256) void gen_basis(bf16_t* __restrict__ B1t,
                                                 bf16_t* __restrict__ B1) {
  const int id = blockIdx.x * 256 + threadIdx.x;   // 131072 threads
  const float C0 = 7.6699039394282061e-4f;         // 2*pi/8192
  if (id < 65536) {
    // B1t half: thread = (k, l/8); writes 8 consecutive l for one k.
    const int l8 = id & 1023, k = id >> 10;        // k in [0,64)
    const int l0 = l8 * 8;
    bf16x8 vc, vs;
#pragma unroll
    for (int j = 0; j < 8; ++j) {
      int r = ((l0 + j) * k) & (L_LEN - 1);
      float s, c;
      sincosf((float)r * C0, &s, &c);
      vc[j] = (bf16_t)c;
      vs[j] = (bf16_t)(-s);
    }
    *(bf16x8*)(B1t + (size_t)k * L_LEN + l0)           = vc;
    *(bf16x8*)(B1t + (size_t)(MODES + k) * L_LEN + l0) = vs;
  } else {
    // B1 half: thread = (l, k/8); writes 8 consecutive comps for one l.
    const int id2 = id - 65536;
    const int k8 = id2 & 7, l = id2 >> 3;          // l in [0,8192)
    const int kk = k8 * 8;
    bf16x8 vc, vs;
#pragma unroll
    for (int j = 0; j < 8; ++j) {
      int r = (l * (kk + j)) & (L_LEN - 1);
      float s, c;
      sincosf((float)r * C0, &s, &c);
      vc[j] = (bf16_t)c;
      vs[j] = (bf16_t)(-s);
    }
    *(bf16x8*)(B1 + (size_t)l * NCOMP + kk)         = vc;
    *(bf16x8*)(B1 + (size_t)l * NCOMP + MODES + kk) = vs;
  }
}

// ---------------------------------------------------------------------------
// W[e][i][o][k] (complex fp32) = lam[k]*cw[i][o][k] + (1-lam[k])*sum_c codes[e][c]*codew[c][i][o][k]
// ---------------------------------------------------------------------------
__global__ void wmix(const float* __restrict__ codes, const float* __restrict__ comw,
                     const float* __restrict__ codew, const float* __restrict__ fw,
                     float* __restrict__ W) {
  int id = blockIdx.x * 256 + threadIdx.x;   // 8*32*32*64 threads
  int k = id & 63;
  int o = (id >> 6) & 31;
  int i = (id >> 11) & 31;
  int e = id >> 16;
  float lam = fminf(fmaxf(fw[k] * (1.0f / 6.0f) + 0.5f, 0.0f), 1.0f);
  float are = 0.f, aim = 0.f;
#pragma unroll
  for (int c = 0; c < 16; ++c) {
    float cd = codes[e * 16 + c];
    const float* p = codew + ((((c * 32 + i) * 32 + o) * 64 + k) << 1);
    are += cd * p[0];
    aim += cd * p[1];
  }
  const float* q = comw + (((i * 32 + o) * 64 + k) << 1);
  float wre = lam * q[0] + (1.f - lam) * are;
  float wim = lam * q[1] + (1.f - lam) * aim;
  float* dst = W + ((((e * 32 + i) * 32 + o) * 64 + k) << 1);
  dst[0] = wre;
  dst[1] = wim;
}

// ---------------------------------------------------------------------------
// Stage 1 (streaming, LDS-free): Xp[sp][4096][128] = x[4096][k-chunk] * B1t^T
// grid = (64 row-tiles, 16 k-splits), 4 waves/block. Each wave owns a
// 16-row x 128-col output tile over a 512-wide K chunk. No barriers, no LDS.
// MFMA frags loaded directly from global:
//   A: lane reads x[m0+(l&15)][k0+(l>>4)*8 ..+8] fp32 -> cvt bf16  (32B/lane)
//   B: lane reads B1t[n0+(l&15)][k0+(l>>4)*8 ..+8] bf16            (16B/lane, L2)
// C frag: row=(lane>>4)*4+reg, col=lane&15. Plain stores to the split's slice.
// ---------------------------------------------------------------------------
__global__ __launch_bounds__(256) void stage1(const float* __restrict__ x,
                                              const bf16_t* __restrict__ B1t,
                                              float* __restrict__ Xp) {
  const int t = threadIdx.x;
  const int lane = t & 63;
  const int w = t >> 6;
  const int l15 = lane & 15, lq = lane >> 4;
  const int m0 = blockIdx.x * 64 + w * 16;
  const int k0 = blockIdx.y * 512;

  const float*  ap = x   + (size_t)(m0 + l15) * L_LEN + k0 + lq * 8;
  const bf16_t* bp = B1t + (size_t)l15 * L_LEN + k0 + lq * 8;

  f32x4 acc[8];
#pragma unroll
  for (int nf = 0; nf < 8; ++nf) acc[nf] = (f32x4){0.f, 0.f, 0.f, 0.f};

  for (int kk = 0; kk < 4; ++kk) {          // 4 outer x 4 inner = 16 k-steps of 32
#pragma unroll
    for (int s = 0; s < 4; ++s) {
      const float4 p0 = *(const float4*)(ap + s * 32);
      const float4 p1 = *(const float4*)(ap + s * 32 + 4);
      bf16x8 av = {(bf16_t)p0.x, (bf16_t)p0.y, (bf16_t)p0.z, (bf16_t)p0.w,
                   (bf16_t)p1.x, (bf16_t)p1.y, (bf16_t)p1.z, (bf16_t)p1.w};
#pragma unroll
      for (int nf = 0; nf < 8; ++nf) {
        bf16x8 bv = *(const bf16x8*)(bp + (size_t)nf * (16 * L_LEN) + s * 32);
        acc[nf] = __builtin_amdgcn_mfma_f32_16x16x32_bf16(av, bv, acc[nf], 0, 0, 0);
      }
    }
    ap += 128;
    bp += 128;
  }

  float* xout = Xp + (size_t)blockIdx.y * (M_ROWS * NCOMP) +
                (size_t)(m0 + lq * 4) * NCOMP + l15;
#pragma unroll
  for (int nf = 0; nf < 8; ++nf)
#pragma unroll
    for (int rg = 0; rg < 4; ++rg)
      xout[(size_t)rg * NCOMP + nf * 16] = acc[nf][rg];
}

// ---------------------------------------------------------------------------
// Mix: per (b,e) block. First reduce the 16 stage1 partials into LDS, then
// Y[b,e,o,k] = sum_i X[b,e,i,k]*W[e,i,o,k], scaled for irfft, emitted as bf16
// A2[m=(b,e,o)][Re k | Im k].
// ---------------------------------------------------------------------------
__global__ __launch_bounds__(256) void mixk(const float* __restrict__ Xp,
                                            const float* __restrict__ W,
                                            bf16_t* __restrict__ A2) {
  __shared__ __align__(16) float Xs[32 * 128];
  const int t = threadIdx.x;
  const int be = blockIdx.x;       // b*8+e
  const int e = be & 7;
  const float* xb = Xp + (size_t)be * (32 * NCOMP);
#pragma unroll
  for (int j = 0; j < 4; ++j) {
    int idx = (t + 256 * j) * 4;
    f32x4 s = (f32x4){0.f, 0.f, 0.f, 0.f};
#pragma unroll
    for (int sp = 0; sp < 16; ++sp)
      s += *(const f32x4*)(xb + (size_t)sp * (M_ROWS * NCOMP) + idx);
    *(f32x4*)(Xs + idx) = s;
  }
  __syncthreads();
  const int k = t & 63;
  const int olo = t >> 6;          // o = olo*8 + j
  float yre[8], yim[8];
#pragma unroll
  for (int j = 0; j < 8; ++j) { yre[j] = 0.f; yim[j] = 0.f; }
  for (int i = 0; i < 32; ++i) {
    float xr = Xs[i * 128 + k];
    float xi = Xs[i * 128 + 64 + k];
    const float* wp = W + ((((e * 32 + i) * 32 + olo * 8) * 64 + k) << 1);
#pragma unroll
    for (int j = 0; j < 8; ++j) {
      float2 wv = *(const float2*)(wp + j * 128);
      yre[j] += xr * wv.x - xi * wv.y;
      yim[j] += xr * wv.y + xi * wv.x;
    }
  }
  float sc = (k == 0) ? (1.0f / 8192.0f) : (2.0f / 8192.0f);  // irfft: DC 1/L, others 2/L
#pragma unroll
  for (int j = 0; j < 8; ++j) {
    int m = be * 32 + olo * 8 + j;
    A2[m * NCOMP + k]         = (bf16_t)(yre[j] * sc);
    A2[m * NCOMP + MODES + k] = (bf16_t)(yim[j] * sc);
  }
}

// ---------------------------------------------------------------------------
// Stage 2 (streaming, LDS-free): out[4096][8192] = A2[4096][128] * B1^T (K=128).
// grid = (64 m-tiles, 64 l-tiles), 4 waves/block; wave owns 16 m x 128 l.
// A/B frags loaded directly from global (A2 1 MiB + B1 2 MiB both L2-resident).
// out[m][l] = sum_k Yre*cos - Yim*sin. Write-BW bound (134 MB out).
// ---------------------------------------------------------------------------
__global__ __launch_bounds__(256) void stage2(const bf16_t* __restrict__ A2,
                                              const bf16_t* __restrict__ B1,
                                              float* __restrict__ out) {
  const int t = threadIdx.x;
  const int lane = t & 63;
  const int w = t >> 6;
  const int l15 = lane & 15, lq = lane >> 4;
  const int m0 = blockIdx.x * 64 + w * 16;
  const int l0 = blockIdx.y * 128;

  const bf16_t* apA = A2 + (size_t)(m0 + l15) * NCOMP + lq * 8;
  const bf16_t* bpB = B1 + (size_t)(l0 + l15) * NCOMP + lq * 8;

  f32x4 acc[8];
#pragma unroll
  for (int nf = 0; nf < 8; ++nf) acc[nf] = (f32x4){0.f, 0.f, 0.f, 0.f};

#pragma unroll 2
  for (int s = 0; s < 4; ++s) {             // K = 128 = 4 steps of 32
    bf16x8 av = *(const bf16x8*)(apA + s * 32);
#pragma unroll
    for (int nf = 0; nf < 8; ++nf) {
      bf16x8 bv = *(const bf16x8*)(bpB + (size_t)nf * (16 * NCOMP) + s * 32);
      acc[nf] = __builtin_amdgcn_mfma_f32_16x16x32_bf16(av, bv, acc[nf], 0, 0, 0);
    }
  }

  float* op = out + (size_t)(m0 + lq * 4) * L_LEN + l0 + l15;
#pragma unroll
  for (int nf = 0; nf < 8; ++nf)
#pragma unroll
    for (int rg = 0; rg < 4; ++rg)
      op[(size_t)rg * L_LEN + nf * 16] = acc[nf][rg];
}

// ---------------------------------------------------------------------------
// ws layout:  [0,2M)   B1t bf16 [128][8192]
//             [2M,4M)  B1  bf16 [8192][128]
//             [4M,20M) W   fp32 [8][32][32][64][2]
//             [20M,21M) A2 bf16 [4096][128]
//             [24M,56M) Xp fp32 [16][4096][128]   (stage1 split-K partials)
// ---------------------------------------------------------------------------
extern "C" void kernel_launch(void* const* d_in, const int* in_sizes, int n_in,
                              void* d_out, int out_size, void* d_ws, size_t ws_size,
                              hipStream_t stream) {
  const float* x     = (const float*)d_in[0];
  const float* codes = (const float*)d_in[1];
  const float* comw  = (const float*)d_in[2];
  const float* codew = (const float*)d_in[3];
  const float* fw    = (const float*)d_in[4];
  float* out = (float*)d_out;
  char* ws = (char*)d_ws;
  bf16_t* B1t = (bf16_t*)(ws);
  bf16_t* B1  = (bf16_t*)(ws + (size_t)(2u << 20));
  float*  W   = (float*) (ws + (size_t)(4u << 20));
  bf16_t* A2  = (bf16_t*)(ws + (size_t)(20u << 20));
  float*  Xp  = (float*) (ws + (size_t)(24u << 20));

  gen_basis<<<512, 256, 0, stream>>>(B1t, B1);
  wmix<<<2048, 256, 0, stream>>>(codes, comw, codew, fw, W);
  stage1<<<dim3(64, SPLITS), 256, 0, stream>>>(x, B1t, Xp);
  mixk<<<128, 256, 0, stream>>>(Xp, W, A2);
  stage2<<<dim3(64, 64), 256, 0, stream>>>(A2, B1, out);
}

// Round 3
// 290.344 us; speedup vs baseline: 1.2707x; 1.2707x over previous
//
#include <hip/hip_runtime.h>
#include <hip/hip_bf16.h>
#include <math.h>
#include <stdint.h>

typedef __bf16 bf16_t;
typedef __bf16 bf16x8 __attribute__((ext_vector_type(8)));
typedef float  f32x4  __attribute__((ext_vector_type(4)));

#define L_LEN 8192
#define MODES 64
#define NCOMP 128      // 2*MODES (Re | Im)
#define M_ROWS 4096    // B * n_env * ch
#define SPLITS 16      // K-splits in stage1 (k-chunk 512 per block)

// async global->LDS, 16B per lane. LDS dst must be wave-uniform base + lane*16.
__device__ __forceinline__ void g2lds16(const void* g, void* l) {
  __builtin_amdgcn_global_load_lds(
      (__attribute__((address_space(1))) void*)(uintptr_t)(g),
      (__attribute__((address_space(3))) void*)(l), 16, 0, 0);
}

// ---------------------------------------------------------------------------
// Basis tables, coalesced 16B stores (each thread emits 8 consecutive dest elems).
// B1t[n][l]  n<64: cos(2*pi*n*l/L)   n>=64: -sin(2*pi*(n-64)*l/L)   [128][8192]
// B1 [l][n]  same values transposed                                  [8192][128]
// ---------------------------------------------------------------------------
__global__ __launch_bounds__(256) void gen_basis(bf16_t* __restrict__ B1t,
                                                 bf16_t* __restrict__ B1) {
  const int id = blockIdx.x * 256 + threadIdx.x;   // 131072 threads
  const float C0 = 7.6699039394282061e-4f;         // 2*pi/8192
  if (id < 65536) {
    const int l8 = id & 1023, k = id >> 10;        // k in [0,64)
    const int l0 = l8 * 8;
    bf16x8 vc, vs;
#pragma unroll
    for (int j = 0; j < 8; ++j) {
      int r = ((l0 + j) * k) & (L_LEN - 1);
      float s, c;
      sincosf((float)r * C0, &s, &c);
      vc[j] = (bf16_t)c;
      vs[j] = (bf16_t)(-s);
    }
    *(bf16x8*)(B1t + (size_t)k * L_LEN + l0)           = vc;
    *(bf16x8*)(B1t + (size_t)(MODES + k) * L_LEN + l0) = vs;
  } else {
    const int id2 = id - 65536;
    const int k8 = id2 & 7, l = id2 >> 3;          // l in [0,8192)
    const int kk = k8 * 8;
    bf16x8 vc, vs;
#pragma unroll
    for (int j = 0; j < 8; ++j) {
      int r = (l * (kk + j)) & (L_LEN - 1);
      float s, c;
      sincosf((float)r * C0, &s, &c);
      vc[j] = (bf16_t)c;
      vs[j] = (bf16_t)(-s);
    }
    *(bf16x8*)(B1 + (size_t)l * NCOMP + kk)         = vc;
    *(bf16x8*)(B1 + (size_t)l * NCOMP + MODES + kk) = vs;
  }
}

// ---------------------------------------------------------------------------
// W[e][i][o][k] (complex fp32) = lam[k]*cw[i][o][k] + (1-lam[k])*sum_c codes[e][c]*codew[c][i][o][k]
// ---------------------------------------------------------------------------
__global__ void wmix(const float* __restrict__ codes, const float* __restrict__ comw,
                     const float* __restrict__ codew, const float* __restrict__ fw,
                     float* __restrict__ W) {
  int id = blockIdx.x * 256 + threadIdx.x;   // 8*32*32*64 threads
  int k = id & 63;
  int o = (id >> 6) & 31;
  int i = (id >> 11) & 31;
  int e = id >> 16;
  float lam = fminf(fmaxf(fw[k] * (1.0f / 6.0f) + 0.5f, 0.0f), 1.0f);
  float are = 0.f, aim = 0.f;
#pragma unroll
  for (int c = 0; c < 16; ++c) {
    float cd = codes[e * 16 + c];
    const float* p = codew + ((((c * 32 + i) * 32 + o) * 64 + k) << 1);
    are += cd * p[0];
    aim += cd * p[1];
  }
  const float* q = comw + (((i * 32 + o) * 64 + k) << 1);
  float wre = lam * q[0] + (1.f - lam) * are;
  float wim = lam * q[1] + (1.f - lam) * aim;
  float* dst = W + ((((e * 32 + i) * 32 + o) * 64 + k) << 1);
  dst[0] = wre;
  dst[1] = wim;
}

// ---------------------------------------------------------------------------
// Stage 1 (hybrid): Xp[sp][4096][128] = x[m-tile][k-chunk] * B1t^T.
// grid = (64 m-tiles, 16 k-splits), 4 waves/block, each wave 16 rows x 128 comps.
// B tile [128 comps][64 k] shared by all 4 waves: double-buffered LDS via
// global_load_lds with XOR swizzle (slot j8 = m8 ^ (n&7)), staged at iteration
// TOP so the __syncthreads vmcnt-drain at iteration END is covered by MFMA.
// A (read once, no reuse): direct global fp32 -> reg, one-iteration prefetch.
// ---------------------------------------------------------------------------
__global__ __launch_bounds__(256, 4) void stage1(const float* __restrict__ x,
                                                 const bf16_t* __restrict__ B1t,
                                                 float* __restrict__ Xp) {
  __shared__ bf16_t Bs[2][128 * 64];   // 2 x 16 KiB, swizzled
  const int t = threadIdx.x;
  const int lane = t & 63;
  const int w = t >> 6;
  const int l15 = lane & 15, lq = lane >> 4;
  const int m0 = blockIdx.x * 64 + w * 16;
  const int k0 = blockIdx.y * 512;

  const float* aptr = x + (size_t)(m0 + l15) * L_LEN + k0 + lq * 8;

  // prologue: stage chunk 0 into buf 0, prefetch A chunk 0
#pragma unroll
  for (int q = 0; q < 4; ++q) {
    int slot = t + 256 * q;
    int n = slot >> 3, m8 = slot & 7, j8 = m8 ^ (n & 7);
    g2lds16(B1t + (size_t)n * L_LEN + k0 + j8 * 8, (char*)(&Bs[0][0]) + slot * 16);
  }
  float4 pa0 = *(const float4*)(aptr + 0);
  float4 pa1 = *(const float4*)(aptr + 4);
  float4 pa2 = *(const float4*)(aptr + 32);
  float4 pa3 = *(const float4*)(aptr + 36);

  f32x4 acc[8];
#pragma unroll
  for (int nf = 0; nf < 8; ++nf) acc[nf] = (f32x4){0.f, 0.f, 0.f, 0.f};

  __syncthreads();   // buf0 staged

#pragma unroll
  for (int ch = 0; ch < 8; ++ch) {
    // 1) kick off next B tile into the other buffer (stays in flight across MFMA)
    if (ch < 7) {
#pragma unroll
      for (int q = 0; q < 4; ++q) {
        int slot = t + 256 * q;
        int n = slot >> 3, m8 = slot & 7, j8 = m8 ^ (n & 7);
        g2lds16(B1t + (size_t)n * L_LEN + k0 + (ch + 1) * 64 + j8 * 8,
                (char*)(&Bs[(ch + 1) & 1][0]) + slot * 16);
      }
    }
    // 2) consume this iteration's A prefetch; issue next iteration's A loads
    float4 a0 = pa0, a1 = pa1, a2 = pa2, a3 = pa3;
    if (ch < 7) {
      const float* ap2 = aptr + (ch + 1) * 64;
      pa0 = *(const float4*)(ap2 + 0);
      pa1 = *(const float4*)(ap2 + 4);
      pa2 = *(const float4*)(ap2 + 32);
      pa3 = *(const float4*)(ap2 + 36);
    }
    bf16x8 av0 = {(bf16_t)a0.x, (bf16_t)a0.y, (bf16_t)a0.z, (bf16_t)a0.w,
                  (bf16_t)a1.x, (bf16_t)a1.y, (bf16_t)a1.z, (bf16_t)a1.w};
    bf16x8 av1 = {(bf16_t)a2.x, (bf16_t)a2.y, (bf16_t)a2.z, (bf16_t)a2.w,
                  (bf16_t)a3.x, (bf16_t)a3.y, (bf16_t)a3.z, (bf16_t)a3.w};
    // 3) MFMA on current buffer
    const bf16_t* bb = &Bs[ch & 1][0];
#pragma unroll
    for (int s = 0; s < 2; ++s) {
      bf16x8 av = s ? av1 : av0;
#pragma unroll
      for (int nf = 0; nf < 8; ++nf) {
        int n = nf * 16 + l15;
        int j8 = (s * 4 + lq) ^ (n & 7);
        bf16x8 bv = *(const bf16x8*)(bb + n * 64 + j8 * 8);
        acc[nf] = __builtin_amdgcn_mfma_f32_16x16x32_bf16(av, bv, acc[nf], 0, 0, 0);
      }
    }
    // 4) single barrier per iteration: next-tile staging had the MFMA phase to land
    __syncthreads();
  }

  float* xout = Xp + (size_t)blockIdx.y * (M_ROWS * NCOMP) +
                (size_t)(m0 + lq * 4) * NCOMP + l15;
#pragma unroll
  for (int nf = 0; nf < 8; ++nf)
#pragma unroll
    for (int rg = 0; rg < 4; ++rg)
      xout[(size_t)rg * NCOMP + nf * 16] = acc[nf][rg];
}

// ---------------------------------------------------------------------------
// Mix: grid (128 be-blocks, 2 o-halves). Reduce the 16 stage1 partials into
// LDS, then Y[b,e,o,k] = sum_i X[b,e,i,k]*W[e,i,o,k], scaled for irfft,
// emitted as bf16 A2[m=(b,e,o)][Re k | Im k].
// ---------------------------------------------------------------------------
__global__ __launch_bounds__(256) void mixk(const float* __restrict__ Xp,
                                            const float* __restrict__ W,
                                            bf16_t* __restrict__ A2) {
  __shared__ __align__(16) float Xs[32 * 128];
  const int t = threadIdx.x;
  const int be = blockIdx.x;       // b*8+e
  const int oh = blockIdx.y;       // o-half: o = olo*8 + oh*4 + j
  const int e = be & 7;
  const float* xb = Xp + (size_t)be * (32 * NCOMP);
#pragma unroll
  for (int j = 0; j < 4; ++j) {
    int idx = (t + 256 * j) * 4;
    f32x4 s = (f32x4){0.f, 0.f, 0.f, 0.f};
#pragma unroll
    for (int sp = 0; sp < 16; ++sp)
      s += *(const f32x4*)(xb + (size_t)sp * (M_ROWS * NCOMP) + idx);
    *(f32x4*)(Xs + idx) = s;
  }
  __syncthreads();
  const int k = t & 63;
  const int olo = t >> 6;          // o = olo*8 + oh*4 + j, j in [0,4)
  float yre[4], yim[4];
#pragma unroll
  for (int j = 0; j < 4; ++j) { yre[j] = 0.f; yim[j] = 0.f; }
  for (int i = 0; i < 32; ++i) {
    float xr = Xs[i * 128 + k];
    float xi = Xs[i * 128 + 64 + k];
    const float* wp = W + ((((e * 32 + i) * 32 + olo * 8 + oh * 4) * 64 + k) << 1);
#pragma unroll
    for (int j = 0; j < 4; ++j) {
      float2 wv = *(const float2*)(wp + j * 128);
      yre[j] += xr * wv.x - xi * wv.y;
      yim[j] += xr * wv.y + xi * wv.x;
    }
  }
  float sc = (k == 0) ? (1.0f / 8192.0f) : (2.0f / 8192.0f);  // irfft: DC 1/L, others 2/L
#pragma unroll
  for (int j = 0; j < 4; ++j) {
    int m = be * 32 + olo * 8 + oh * 4 + j;
    A2[m * NCOMP + k]         = (bf16_t)(yre[j] * sc);
    A2[m * NCOMP + MODES + k] = (bf16_t)(yim[j] * sc);
  }
}

// ---------------------------------------------------------------------------
// Stage 2 (hybrid): out[4096][8192] = A2[4096][128] * B1^T (K=128, one shot).
// grid = (64 m-tiles, 64 l-tiles), 4 waves/block; wave: 16 m x 128 l.
// B1 tile (shared x4 waves) staged to LDS (32 KiB -> 5 blocks/CU); A2 frags
// direct global->reg issued BEFORE the barrier so they ride the staging wait.
// ---------------------------------------------------------------------------
__global__ __launch_bounds__(256) void stage2(const bf16_t* __restrict__ A2,
                                              const bf16_t* __restrict__ B1,
                                              float* __restrict__ out) {
  __shared__ bf16_t Bs[128 * 128];   // 32 KiB, swizzled (16 slots/row)
  const int t = threadIdx.x;
  const int lane = t & 63;
  const int w = t >> 6;
  const int l15 = lane & 15, lq = lane >> 4;
  const int m0 = blockIdx.x * 64 + w * 16;
  const int l0 = blockIdx.y * 128;

#pragma unroll
  for (int q = 0; q < 8; ++q) {
    int slot = t + 256 * q;
    int lr = slot >> 4, m16 = slot & 15, j8 = m16 ^ (lr & 15);
    g2lds16(B1 + (size_t)(l0 + lr) * NCOMP + j8 * 8, (char*)Bs + slot * 16);
  }
  const bf16_t* ap = A2 + (size_t)(m0 + l15) * NCOMP + lq * 8;
  bf16x8 av[4];
#pragma unroll
  for (int s = 0; s < 4; ++s) av[s] = *(const bf16x8*)(ap + s * 32);

  f32x4 acc[8];
#pragma unroll
  for (int nf = 0; nf < 8; ++nf) acc[nf] = (f32x4){0.f, 0.f, 0.f, 0.f};

  __syncthreads();

#pragma unroll
  for (int s = 0; s < 4; ++s) {
#pragma unroll
    for (int nf = 0; nf < 8; ++nf) {
      int lr = nf * 16 + l15;
      int j8 = (s * 4 + lq) ^ (lr & 15);
      bf16x8 bv = *(const bf16x8*)(Bs + lr * 128 + j8 * 8);
      acc[nf] = __builtin_amdgcn_mfma_f32_16x16x32_bf16(av[s], bv, acc[nf], 0, 0, 0);
    }
  }

  float* op = out + (size_t)(m0 + lq * 4) * L_LEN + l0 + l15;
#pragma unroll
  for (int nf = 0; nf < 8; ++nf)
#pragma unroll
    for (int rg = 0; rg < 4; ++rg)
      op[(size_t)rg * L_LEN + nf * 16] = acc[nf][rg];
}

// ---------------------------------------------------------------------------
// ws layout:  [0,2M)   B1t bf16 [128][8192]
//             [2M,4M)  B1  bf16 [8192][128]
//             [4M,20M) W   fp32 [8][32][32][64][2]
//             [20M,21M) A2 bf16 [4096][128]
//             [24M,56M) Xp fp32 [16][4096][128]   (stage1 split-K partials)
// ---------------------------------------------------------------------------
extern "C" void kernel_launch(void* const* d_in, const int* in_sizes, int n_in,
                              void* d_out, int out_size, void* d_ws, size_t ws_size,
                              hipStream_t stream) {
  const float* x     = (const float*)d_in[0];
  const float* codes = (const float*)d_in[1];
  const float* comw  = (const float*)d_in[2];
  const float* codew = (const float*)d_in[3];
  const float* fw    = (const float*)d_in[4];
  float* out = (float*)d_out;
  char* ws = (char*)d_ws;
  bf16_t* B1t = (bf16_t*)(ws);
  bf16_t* B1  = (bf16_t*)(ws + (size_t)(2u << 20));
  float*  W   = (float*) (ws + (size_t)(4u << 20));
  bf16_t* A2  = (bf16_t*)(ws + (size_t)(20u << 20));
  float*  Xp  = (float*) (ws + (size_t)(24u << 20));

  gen_basis<<<512, 256, 0, stream>>>(B1t, B1);
  wmix<<<2048, 256, 0, stream>>>(codes, comw, codew, fw, W);
  stage1<<<dim3(64, SPLITS), 256, 0, stream>>>(x, B1t, Xp);
  mixk<<<dim3(128, 2), 256, 0, stream>>>(Xp, W, A2);
  stage2<<<dim3(64, 64), 256, 0, stream>>>(A2, B1, out);
}